// Round 6
// baseline (2435.442 us; speedup 1.0000x reference)
//
#include <hip/hip_runtime.h>

#define TT 2048
#define LL 50
#define DD 300
#define HH 100
#define NCC 7

typedef unsigned short u16;
typedef unsigned int u32;
typedef _Float16 f16x2 __attribute__((ext_vector_type(2)));
typedef _Float16 f16x8 __attribute__((ext_vector_type(8)));
typedef float f32x4 __attribute__((ext_vector_type(4)));

__device__ __forceinline__ float frcp(float x){ return __builtin_amdgcn_rcpf(x); }
__device__ __forceinline__ float sigm(float x){ return frcp(1.f + __expf(-x)); }
__device__ __forceinline__ float ftanh(float x){ return 1.f - 2.f * frcp(1.f + __expf(2.f * x)); }

#if defined(__has_builtin)
#if __has_builtin(__builtin_amdgcn_fdot2)
#define HAS_FDOT2 1
#endif
#endif
__device__ __forceinline__ float fdot2(f16x2 a, f16x2 b, float c){
#ifdef HAS_FDOT2
  return __builtin_amdgcn_fdot2(a, b, c, false);
#else
  return c + (float)a.x * (float)b.x + (float)a.y * (float)b.y;
#endif
}
__device__ __forceinline__ f16x2 pk(float x, float y){ f16x2 r; r.x = (_Float16)x; r.y = (_Float16)y; return r; }

// ---------------- Kernel 0: pack conv weights into MFMA B-fragment order ----------------
// 480 tiles: kk=3: tiles [0,120) (4 ntiles x 30 kt); kk=4: [120,280); kk=5: [280,480).
// Tile chunk = 512 f16 = one 32x16 B-tile in lane order: elem (lane,i) = B[k][n],
// k = kt*32 + (lane>>4)*8 + i, n = ntile*16 + (lane&15); B[k][n] = W[n][j][d],
// j = k/320, d = k%320 (d>=300 zero-padded). K padded to 320 per tap so 32-k
// tiles never straddle a tap boundary.
__global__ __launch_bounds__(256) void k_prep(const float* __restrict__ Wc3,
    const float* __restrict__ Wc4, const float* __restrict__ Wc5, _Float16* __restrict__ wtp)
{
  const int t = blockIdx.x;
  int kki, ntile, kt;
  if (t < 120){ kki = 0; ntile = t / 30;        kt = t % 30; }
  else if (t < 280){ kki = 1; int r = t - 120; ntile = r / 40; kt = r % 40; }
  else { kki = 2; int r = t - 280;             ntile = r / 50; kt = r % 50; }
  const float* W = (kki == 0) ? Wc3 : ((kki == 1) ? Wc4 : Wc5);
  const int kk = 3 + kki;
  #pragma unroll
  for (int u = 0; u < 2; ++u){
    int e = threadIdx.x * 2 + u;       // 0..511
    int lane = e >> 3, i = e & 7;
    int k = kt * 32 + (lane >> 4) * 8 + i;
    int f = ntile * 16 + (lane & 15);
    int j = k / 320, d = k - j * 320;
    float v = (d < DD) ? W[((size_t)f * kk + j) * DD + d] : 0.f;
    wtp[(size_t)t * 512 + e] = (_Float16)v;
  }
}

// ---------------- Kernel 1: embedding + TextCNN(3,4,5) via MFMA + max-relu + s_utt ----------------
// Per block = 1 sentence, 4 waves. Wave w owns n-tile w (filters 16w..16w+15).
// A = sliding-window rows of the f16 embedding tile in LDS ([52][328] f16; row
// stride 164 words = 4 mod 32 -> 2-way bank aliasing, free per m136).
// B = packed fragments from k_prep (coalesced dwordx4 from L2).
// 3 m-tile accumulators live across K so B is loaded once per k-tile.
#define WST 328
__global__ __launch_bounds__(256) void k_cnn(const int* __restrict__ sents,
    const float* __restrict__ emb, const _Float16* __restrict__ wtp,
    const float* __restrict__ bc3, const float* __restrict__ bc4, const float* __restrict__ bc5,
    const float* __restrict__ Wt,  const float* __restrict__ bt,
    float* __restrict__ su)
{
  __shared__ __attribute__((aligned(16))) _Float16 w16[52 * WST];
  __shared__ float feats[192];
  __shared__ int ids[LL];
  const int tid = threadIdx.x;
  const int s = blockIdx.x;

  if (tid < LL) ids[tid] = sents[s * LL + tid];
  for (int e = tid; e < 52 * WST / 2; e += 256) ((u32*)w16)[e] = 0u;
  __syncthreads();
  for (int e = tid; e < LL * 75; e += 256){
    int l = e / 75, d4 = (e - l * 75) * 4;
    float4 v = *(const float4*)&emb[(size_t)ids[l] * DD + d4];
    _Float16* p = &w16[l * WST + d4];
    p[0] = (_Float16)v.x; p[1] = (_Float16)v.y; p[2] = (_Float16)v.z; p[3] = (_Float16)v.w;
  }
  __syncthreads();

  const int lane = tid & 63, wid = tid >> 6;
  const int rl = lane & 15, gp = lane >> 4;
  const int kkstart[3] = {0, 120, 280};
  float fmaxv[3];
  #pragma unroll
  for (int kki = 0; kki < 3; ++kki){
    const int kk = 3 + kki, nkt = kk * 10, Pk = LL - kk + 1;
    f32x4 acc0 = {0.f,0.f,0.f,0.f}, acc1 = acc0, acc2 = acc0;
    const f16x8* bp = (const f16x8*)(wtp + (size_t)(kkstart[kki] + wid * nkt) * 512) + lane;
    int j = 0, d = gp * 8;
    for (int kt = 0; kt < nkt; ++kt){
      f16x8 b  = bp[(size_t)kt * 64];
      f16x8 a0 = *(const f16x8*)&w16[(rl      + j) * WST + d];
      f16x8 a1 = *(const f16x8*)&w16[(16 + rl + j) * WST + d];
      f16x8 a2 = *(const f16x8*)&w16[(32 + rl + j) * WST + d];
      acc0 = __builtin_amdgcn_mfma_f32_16x16x32_f16(a0, b, acc0, 0, 0, 0);
      acc1 = __builtin_amdgcn_mfma_f32_16x16x32_f16(a1, b, acc1, 0, 0, 0);
      acc2 = __builtin_amdgcn_mfma_f32_16x16x32_f16(a2, b, acc2, 0, 0, 0);
      d += 32; if (d >= 320){ d -= 320; ++j; }
    }
    // D layout: col = lane&15 (filter), row = gp*4 + r (position in m-tile)
    float m = -1e30f;
    #pragma unroll
    for (int r = 0; r < 4; ++r){
      int p0 = gp * 4 + r;
      if (p0 < Pk)      m = fmaxf(m, acc0[r]);
      if (16 + p0 < Pk) m = fmaxf(m, acc1[r]);
      if (32 + p0 < Pk) m = fmaxf(m, acc2[r]);
    }
    m = fmaxf(m, __shfl_xor(m, 16));
    m = fmaxf(m, __shfl_xor(m, 32));
    fmaxv[kki] = m;
  }
  if (lane < 16){
    feats[  0 + wid * 16 + lane] = fmaxv[0];
    feats[ 64 + wid * 16 + lane] = fmaxv[1];
    feats[128 + wid * 16 + lane] = fmaxv[2];
  }
  __syncthreads();
  if (tid < 192){
    float bias = (tid < 64) ? bc3[tid] : ((tid < 128) ? bc4[tid - 64] : bc5[tid - 128]);
    feats[tid] = fmaxf(0.f, feats[tid] + bias);
  }
  __syncthreads();
  if (tid < HH){
    float acc = bt[tid];
    for (int c = 0; c < 192; ++c)
      acc += feats[c] * Wt[c * HH + tid];
    su[(size_t)s * HH + tid] = ftanh(acc);
  }
}

// ---------------- Kernel 2/4: gi = src @ Wih^T + bih   (rows x 300) ----------------
__global__ __launch_bounds__(320) void k_gi(const float* __restrict__ src,
    const float* __restrict__ W, const float* __restrict__ b, float* __restrict__ dst)
{
  __shared__ float x[HH];
  const int t = blockIdx.x, tid = threadIdx.x;
  if (tid < HH) x[tid] = src[(size_t)t * HH + tid];
  __syncthreads();
  if (tid < 300){
    float acc = b[tid];
    const float* wr = W + (size_t)tid * HH;
    #pragma unroll
    for (int i = 0; i < 25; ++i){
      float4 wv = *(const float4*)(wr + 4 * i);
      float4 xv = *(const float4*)&x[4 * i];
      acc += xv.x * wv.x + xv.y * wv.y + xv.z * wv.z + xv.w * wv.w;
    }
    dst[(size_t)t * 300 + tid] = acc;
  }
}

// ---------------- Kernel 3: sequential context-GRU scan (1 workgroup, 320 thr) ----------------
// ONE barrier + ONE LDS hop per step. Whh rows packed as p = unit*4 + gate
// (gate 3 = zero pad; 400 rows = 25 m-tiles), so the MFMA D layout
// (row = gp*4+reg) delivers r,z,n of ONE unit into acc[0..2] of a lane:
// the gate combine is IN-LANE (no gh LDS round-trip, no second barrier).
// D cols are 16 replicas; lane (rl,gp) holds all 5 of its wave's m-tiles,
// msel = rl%5 cndmask-selects one -> 100 combines spread across lanes.
// Writers rl<5 store new h (f16) to a DOUBLE-BUFFERED h16; the double buffer
// is what makes one barrier/step race-free (write buf != read buf; barrier
// separates step-s writes from step-s+1 reads of the same buf).
// Whh A-fragments persist in registers (5x4 f16x8 = 80 VGPR), loaded once.
#define CH 32
__global__ __launch_bounds__(320, 1) void k_scan(const float* __restrict__ gi,
    const float* __restrict__ Whh, const float* __restrict__ bhh,
    float* __restrict__ hid, int steps)
{
  __shared__ __attribute__((aligned(16))) _Float16 hA[128];
  __shared__ __attribute__((aligned(16))) _Float16 hB[128];
  __shared__ float gi_buf[CH * 300];
  __shared__ float hid_buf[CH * HH];
  const int tid = threadIdx.x;
  const int lane = tid & 63, wvid = tid >> 6;   // 5 waves
  const int rl = lane & 15, gp = lane >> 4;

  // persistent A-fragments: wave w owns m-tiles 5w..5w+4 (units 20w..20w+19)
  // packed row p = mt*16 + rl -> unit mt*4+(rl>>2), gate rl&3; Whh row = unit + 100*gate
  f16x8 afrag[5][4];
  #pragma unroll
  for (int m = 0; m < 5; ++m){
    const int mt = wvid * 5 + m;
    const int uu = mt * 4 + (rl >> 2), g = rl & 3;
    #pragma unroll
    for (int kt = 0; kt < 4; ++kt){
      f16x8 f;
      #pragma unroll
      for (int i = 0; i < 8; ++i){
        int k = kt * 32 + gp * 8 + i;
        float v = (g < 3 && k < 100) ? Whh[(size_t)(uu + 100 * g) * 100 + k] : 0.f;
        f[i] = (_Float16)v;
      }
      afrag[m][kt] = f;
    }
  }
  const int msel = rl % 5;                      // which owned m-tile this lane combines
  const int u = wvid * 20 + msel * 4 + gp;      // its unit (always < 100)
  const float bhr = bhh[u], bhz = bhh[u + 100], bhn = bhh[u + 200];
  float hreg = 0.f;
  if (tid < 128){ hA[tid] = (_Float16)0.f; hB[tid] = (_Float16)0.f; }
  {
    int c0 = (steps < CH ? steps : CH) * 75;
    for (int e = tid; e < c0; e += 320)
      ((float4*)gi_buf)[e] = ((const float4*)gi)[e];
  }
  __syncthreads();

  int t0 = 0;
  while (t0 < steps){
    int cnt = steps - t0; if (cnt > CH) cnt = CH;
    for (int s = 0; s < cnt; ++s){
      const int st = t0 + s;
      const _Float16* hs = (st & 1) ? hB : hA;   // read state t
      _Float16*       hd = (st & 1) ? hA : hB;   // write state t+1
      // gi reads issued early; latency hides under MFMAs
      float gir = gi_buf[s * 300 + u];
      float giz = gi_buf[s * 300 + 100 + u];
      float gin = gi_buf[s * 300 + 200 + u];
      const f16x8* hp = (const f16x8*)hs;
      f16x8 bf0 = hp[0 + gp], bf1 = hp[4 + gp], bf2 = hp[8 + gp], bf3 = hp[12 + gp];
      f32x4 a0 = {0.f,0.f,0.f,0.f}, a1 = a0, a2 = a0, a3 = a0, a4 = a0;
      a0 = __builtin_amdgcn_mfma_f32_16x16x32_f16(afrag[0][0], bf0, a0, 0, 0, 0);
      a1 = __builtin_amdgcn_mfma_f32_16x16x32_f16(afrag[1][0], bf0, a1, 0, 0, 0);
      a2 = __builtin_amdgcn_mfma_f32_16x16x32_f16(afrag[2][0], bf0, a2, 0, 0, 0);
      a3 = __builtin_amdgcn_mfma_f32_16x16x32_f16(afrag[3][0], bf0, a3, 0, 0, 0);
      a4 = __builtin_amdgcn_mfma_f32_16x16x32_f16(afrag[4][0], bf0, a4, 0, 0, 0);
      a0 = __builtin_amdgcn_mfma_f32_16x16x32_f16(afrag[0][1], bf1, a0, 0, 0, 0);
      a1 = __builtin_amdgcn_mfma_f32_16x16x32_f16(afrag[1][1], bf1, a1, 0, 0, 0);
      a2 = __builtin_amdgcn_mfma_f32_16x16x32_f16(afrag[2][1], bf1, a2, 0, 0, 0);
      a3 = __builtin_amdgcn_mfma_f32_16x16x32_f16(afrag[3][1], bf1, a3, 0, 0, 0);
      a4 = __builtin_amdgcn_mfma_f32_16x16x32_f16(afrag[4][1], bf1, a4, 0, 0, 0);
      a0 = __builtin_amdgcn_mfma_f32_16x16x32_f16(afrag[0][2], bf2, a0, 0, 0, 0);
      a1 = __builtin_amdgcn_mfma_f32_16x16x32_f16(afrag[1][2], bf2, a1, 0, 0, 0);
      a2 = __builtin_amdgcn_mfma_f32_16x16x32_f16(afrag[2][2], bf2, a2, 0, 0, 0);
      a3 = __builtin_amdgcn_mfma_f32_16x16x32_f16(afrag[3][2], bf2, a3, 0, 0, 0);
      a4 = __builtin_amdgcn_mfma_f32_16x16x32_f16(afrag[4][2], bf2, a4, 0, 0, 0);
      a0 = __builtin_amdgcn_mfma_f32_16x16x32_f16(afrag[0][3], bf3, a0, 0, 0, 0);
      a1 = __builtin_amdgcn_mfma_f32_16x16x32_f16(afrag[1][3], bf3, a1, 0, 0, 0);
      a2 = __builtin_amdgcn_mfma_f32_16x16x32_f16(afrag[2][3], bf3, a2, 0, 0, 0);
      a3 = __builtin_amdgcn_mfma_f32_16x16x32_f16(afrag[3][3], bf3, a3, 0, 0, 0);
      a4 = __builtin_amdgcn_mfma_f32_16x16x32_f16(afrag[4][3], bf3, a4, 0, 0, 0);
      // in-lane gate combine for unit u (cndmask select of the owned m-tile)
      float ghr = msel==0 ? a0[0] : msel==1 ? a1[0] : msel==2 ? a2[0] : msel==3 ? a3[0] : a4[0];
      float ghz = msel==0 ? a0[1] : msel==1 ? a1[1] : msel==2 ? a2[1] : msel==3 ? a3[1] : a4[1];
      float ghn = msel==0 ? a0[2] : msel==1 ? a1[2] : msel==2 ? a2[2] : msel==3 ? a3[2] : a4[2];
      float r = sigm(gir + ghr + bhr);
      float z = sigm(giz + ghz + bhz);
      float n = ftanh(gin + r * (ghn + bhn));
      float o = (1.f - z) * n + z * hreg;
      hreg = o;
      if (rl < 5){                               // one writer per unit (rl == msel)
        hd[u] = (_Float16)o;
        hid_buf[s * HH + u] = o;
      }
      __syncthreads();
    }
    // chunk boundary: flush hid, stage next gi chunk
    for (int e = tid; e < cnt * 25; e += 320)
      ((float4*)(hid + (size_t)t0 * HH))[e] = ((const float4*)hid_buf)[e];
    int nt0 = t0 + cnt;
    int ncnt = steps - nt0; if (ncnt > CH) ncnt = CH; if (ncnt < 0) ncnt = 0;
    for (int e = tid; e < ncnt * 75; e += 320)
      ((float4*)gi_buf)[e] = ((const float4*)(gi + (size_t)nt0 * 300))[e];
    __syncthreads();
    t0 = nt0;
  }
}

// ---------------- Kernel 5: 3-hop windowed memory attention (1 block / query) ----------------
__global__ __launch_bounds__(320) void k_att(
    const float* __restrict__ su, const float* __restrict__ hid, const float* __restrict__ gm,
    const float* __restrict__ Wih, const float* __restrict__ Whh,
    const float* __restrict__ bih, const float* __restrict__ bhh,
    float* __restrict__ scont)
{
  __shared__ float mem_l[40 * 104];
  __shared__ __attribute__((aligned(16))) _Float16 mem16[40 * 104];
  __shared__ float hbuf[HH];
  __shared__ __attribute__((aligned(16))) _Float16 hb16[104];
  __shared__ float gh_l[300];
  __shared__ float q_l[104];
  __shared__ float sc_l[40];
  __shared__ float bi_l[300];
  __shared__ _Float16 g_l[40 * 300];   // hop0: staged gm; hop1: computed gi2
  const int tid = threadIdx.x;
  const int q = blockIdx.x;                 // query q -> sentence q+1
  int wmin = 39 - q; if (wmin < 0) wmin = 0;
  f16x2 wreg[52];
  float bh = 0.f;

  if (tid < 300){ bi_l[tid] = bih[tid]; bh = bhh[tid]; }
  if (tid < 104) q_l[tid] = (tid < 100) ? su[(size_t)(q + 1) * HH + tid] : 0.f;
  for (int e = tid; e < 40 * 104; e += 320){
    int w = e / 104, i = e - w * 104;
    float v = 0.f;
    if (i < 100 && w >= wmin) v = hid[(size_t)(q - 39 + w) * HH + i];
    mem_l[e] = v;
    mem16[e] = (_Float16)v;   // also zeroes pads (cols 100..103)
  }
  for (int e = tid; e < 40 * 300; e += 320){
    int w = e / 300, j = e - w * 300;
    float v = (w >= wmin) ? gm[(size_t)(q - 39 + w) * 300 + j] : 0.f;
    g_l[e] = (_Float16)v;
  }
  if (tid < 300){
    const float* r0 = Whh + (size_t)tid * 100;
    #pragma unroll
    for (int i = 0; i < 25; ++i){
      float4 a = *(const float4*)(r0 + 4 * i);
      wreg[2*i] = pk(a.x, a.y); wreg[2*i+1] = pk(a.z, a.w);
    }
  }
  wreg[50] = pk(0,0); wreg[51] = pk(0,0);
  __syncthreads();

  for (int hop = 0; hop < 3; ++hop){
    // --- attention: scores ---
    if (tid < 40){
      float a0 = 0, a1 = 0, a2 = 0, a3 = 0;
      const float* mr = &mem_l[tid * 104];
      #pragma unroll
      for (int i = 0; i < 25; ++i){
        float4 m4 = *(const float4*)&mr[4 * i];
        float4 q4 = *(const float4*)&q_l[4 * i];
        a0 += m4.x * q4.x; a1 += m4.y * q4.y; a2 += m4.z * q4.z; a3 += m4.w * q4.w;
      }
      sc_l[tid] = (tid >= wmin) ? ((a0 + a1) + (a2 + a3)) : -1e10f;
    }
    __syncthreads();
    if (tid < 64){
      float v = (tid < 40) ? sc_l[tid] : -3e38f;
      float m = v;
      #pragma unroll
      for (int off = 32; off; off >>= 1) m = fmaxf(m, __shfl_xor(m, off));
      float e = (tid < 40) ? __expf(v - m) : 0.f;
      float ssum = e;
      #pragma unroll
      for (int off = 32; off; off >>= 1) ssum += __shfl_xor(ssum, off);
      if (tid < 40) sc_l[tid] = e * frcp(ssum);
    }
    __syncthreads();
    // --- attention: context + query update ---
    if (tid < 50){
      float c0 = 0.f, c1 = 0.f;
      for (int w = wmin; w < 40; ++w){
        float a = sc_l[w];
        float2 mv = *(const float2*)&mem_l[w * 104 + 2 * tid];
        c0 += a * mv.x; c1 += a * mv.y;
      }
      float q0 = ftanh(q_l[2 * tid]     + c0);
      float q1 = ftanh(q_l[2 * tid + 1] + c1);
      *(float2*)&q_l[2 * tid] = make_float2(q0, q1);
      if (hop == 2)
        *(float2*)&scont[(size_t)(q + 1) * HH + 2 * tid] = make_float2(q0, q1);
    }
    if (hop == 2) break;

    if (hop == 1){
      // g_l = mem @ Wih^T + bih  (mem16 is post-scan1 state)
      if (tid < 300){
        const float* r0 = Wih + (size_t)tid * 100;
        #pragma unroll
        for (int i = 0; i < 25; ++i){
          float4 a = *(const float4*)(r0 + 4 * i);
          wreg[2*i] = pk(a.x, a.y); wreg[2*i+1] = pk(a.z, a.w);
        }
        for (int w = 0; w < 40; ++w){
          float a0 = 0, a1 = 0;
          const float4* mq = (const float4*)&mem16[w * 104];
          #pragma unroll
          for (int g = 0; g < 13; ++g){
            float4 hv = mq[g];
            a0 = fdot2(wreg[4*g  ], __builtin_bit_cast(f16x2, hv.x), a0);
            a1 = fdot2(wreg[4*g+1], __builtin_bit_cast(f16x2, hv.y), a1);
            a0 = fdot2(wreg[4*g+2], __builtin_bit_cast(f16x2, hv.z), a0);
            a1 = fdot2(wreg[4*g+3], __builtin_bit_cast(f16x2, hv.w), a1);
          }
          g_l[w * 300 + tid] = (_Float16)(a0 + a1 + bi_l[tid]);
        }
        // restore Whh for scan2
        const float* rh = Whh + (size_t)tid * 100;
        #pragma unroll
        for (int i = 0; i < 25; ++i){
          float4 a = *(const float4*)(rh + 4 * i);
          wreg[2*i] = pk(a.x, a.y); wreg[2*i+1] = pk(a.z, a.w);
        }
      }
    }

    // --- memory GRU scan over the 40 slots ---
    if (tid < HH) hbuf[tid] = 0.f;
    if (tid < 104) hb16[tid] = (_Float16)0.f;
    __syncthreads();   // also orders g_l writes (hop1) before scan reads
    for (int w = 0; w < 40; ++w){
      if (tid < 300){
        float a0 = 0, a1 = 0;
        const float4* hq = (const float4*)hb16;
        #pragma unroll
        for (int g = 0; g < 13; ++g){
          float4 hv = hq[g];
          a0 = fdot2(wreg[4*g  ], __builtin_bit_cast(f16x2, hv.x), a0);
          a1 = fdot2(wreg[4*g+1], __builtin_bit_cast(f16x2, hv.y), a1);
          a0 = fdot2(wreg[4*g+2], __builtin_bit_cast(f16x2, hv.z), a0);
          a1 = fdot2(wreg[4*g+3], __builtin_bit_cast(f16x2, hv.w), a1);
        }
        gh_l[tid] = a0 + a1 + bh;
      }
      __syncthreads();
      if (tid < HH){
        float o = hbuf[tid];
        if (w >= wmin){
          const _Float16* gp = &g_l[w * 300];
          float gir = (float)gp[tid], giz = (float)gp[tid + 100], gin = (float)gp[tid + 200];
          float r = sigm(gir + gh_l[tid]);
          float z = sigm(giz + gh_l[tid + 100]);
          float n = ftanh(gin + r * gh_l[tid + 200]);
          o = (1.f - z) * n + z * o;
        }
        hbuf[tid] = o;
        hb16[tid] = (_Float16)o;
        mem_l[w * 104 + tid] = o;
        mem16[w * 104 + tid] = (_Float16)o;
      }
      __syncthreads();
    }
  }
}

// ---------------- Kernel 6: classifier + log_softmax ----------------
__global__ __launch_bounds__(256) void k_cls(const float* __restrict__ su, const float* __restrict__ scont,
    const float* __restrict__ Wcls, const float* __restrict__ bcls, float* __restrict__ out)
{
  __shared__ float wl[HH * NCC];
  __shared__ float bl[NCC];
  const int tid = threadIdx.x;
  for (int e = tid; e < HH * NCC; e += 256) wl[e] = Wcls[e];
  if (tid < NCC) bl[tid] = bcls[tid];
  __syncthreads();
  int r = blockIdx.x * 256 + tid;
  if (r < TT){
    const float* v = (r == 0) ? su : (scont + (size_t)r * HH);
    float l[NCC];
    #pragma unroll
    for (int c = 0; c < NCC; ++c) l[c] = bl[c];
    for (int h = 0; h < HH; ++h){
      float x = v[h];
      #pragma unroll
      for (int c = 0; c < NCC; ++c) l[c] += x * wl[h * NCC + c];
    }
    float m = l[0];
    #pragma unroll
    for (int c = 1; c < NCC; ++c) m = fmaxf(m, l[c]);
    float ssum = 0.f;
    #pragma unroll
    for (int c = 0; c < NCC; ++c) ssum += __expf(l[c] - m);
    float lse = m + __logf(ssum);
    #pragma unroll
    for (int c = 0; c < NCC; ++c) out[(size_t)r * NCC + c] = l[c] - lse;
  }
}

extern "C" void kernel_launch(void* const* d_in, const int* in_sizes, int n_in,
                              void* d_out, int out_size, void* d_ws, size_t ws_size,
                              hipStream_t stream)
{
  const int* sents  = (const int*)d_in[0];
  // d_in[1] = lengths (unused by the reference)
  const float* emb    = (const float*)d_in[2];
  const float* Wc3    = (const float*)d_in[3];  const float* bc3 = (const float*)d_in[4];
  const float* Wc4    = (const float*)d_in[5];  const float* bc4 = (const float*)d_in[6];
  const float* Wc5    = (const float*)d_in[7];  const float* bc5 = (const float*)d_in[8];
  const float* Wt     = (const float*)d_in[9];  const float* bt  = (const float*)d_in[10];
  const float* Wih_c  = (const float*)d_in[11]; const float* Whh_c = (const float*)d_in[12];
  const float* bih_c  = (const float*)d_in[13]; const float* bhh_c = (const float*)d_in[14];
  const float* Wih_m  = (const float*)d_in[15]; const float* Whh_m = (const float*)d_in[16];
  const float* bih_m  = (const float*)d_in[17]; const float* bhh_m = (const float*)d_in[18];
  const float* Wcls   = (const float*)d_in[19]; const float* bcls  = (const float*)d_in[20];

  float* ws    = (float*)d_ws;
  float* su    = ws;                  // 2048*100
  float* gic   = su  + 204800;        // 2047*300 (dead after k_scan)
  float* hid   = gic + 614100;        // 2047*100
  float* gm    = gic;                 // aliases gic (gic consumed before gm written)
  float* scont = hid + 204700;        // 2048*100 (row 0 unused)
  _Float16* wtp = (_Float16*)(scont + 204800);   // 245760 f16 packed conv weights

  k_prep<<<480,     256, 0, stream>>>(Wc3, Wc4, Wc5, wtp);
  k_cnn <<<TT,      256, 0, stream>>>(sents, emb, wtp, bc3, bc4, bc5, Wt, bt, su);
  k_gi  <<<TT - 1,  320, 0, stream>>>(su, Wih_c, bih_c, gic);
  k_scan<<<1,       320, 0, stream>>>(gic, Whh_c, bhh_c, hid, TT - 1);
  k_gi  <<<TT - 1,  320, 0, stream>>>(hid, Wih_m, bih_m, gm);
  k_att <<<TT - 1,  320, 0, stream>>>(su, hid, gm, Wih_m, Whh_m, bih_m, bhh_m, scont);
  k_cls <<<(TT + 255) / 256, 256, 0, stream>>>(su, scont, Wcls, bcls, (float*)d_out);
}

// Round 7
// 1744.363 us; speedup vs baseline: 1.3962x; 1.3962x over previous
//
#include <hip/hip_runtime.h>

#define TT 2048
#define LL 50
#define DD 300
#define HH 100
#define NCC 7

typedef unsigned short u16;
typedef unsigned int u32;
typedef _Float16 f16x2 __attribute__((ext_vector_type(2)));
typedef _Float16 f16x4 __attribute__((ext_vector_type(4)));
typedef _Float16 f16x8 __attribute__((ext_vector_type(8)));
typedef float f32x4 __attribute__((ext_vector_type(4)));

__device__ __forceinline__ float frcp(float x){ return __builtin_amdgcn_rcpf(x); }
__device__ __forceinline__ float sigm(float x){ return frcp(1.f + __expf(-x)); }
__device__ __forceinline__ float ftanh(float x){ return 1.f - 2.f * frcp(1.f + __expf(2.f * x)); }

#if defined(__has_builtin)
#if __has_builtin(__builtin_amdgcn_fdot2)
#define HAS_FDOT2 1
#endif
#endif
__device__ __forceinline__ float fdot2(f16x2 a, f16x2 b, float c){
#ifdef HAS_FDOT2
  return __builtin_amdgcn_fdot2(a, b, c, false);
#else
  return c + (float)a.x * (float)b.x + (float)a.y * (float)b.y;
#endif
}
__device__ __forceinline__ f16x2 pk(float x, float y){ f16x2 r; r.x = (_Float16)x; r.y = (_Float16)y; return r; }

// ---------------- Kernel 0: pack conv weights into MFMA B-fragment order ----------------
__global__ __launch_bounds__(256) void k_prep(const float* __restrict__ Wc3,
    const float* __restrict__ Wc4, const float* __restrict__ Wc5, _Float16* __restrict__ wtp)
{
  const int t = blockIdx.x;
  int kki, ntile, kt;
  if (t < 120){ kki = 0; ntile = t / 30;        kt = t % 30; }
  else if (t < 280){ kki = 1; int r = t - 120; ntile = r / 40; kt = r % 40; }
  else { kki = 2; int r = t - 280;             ntile = r / 50; kt = r % 50; }
  const float* W = (kki == 0) ? Wc3 : ((kki == 1) ? Wc4 : Wc5);
  const int kk = 3 + kki;
  #pragma unroll
  for (int u = 0; u < 2; ++u){
    int e = threadIdx.x * 2 + u;       // 0..511
    int lane = e >> 3, i = e & 7;
    int k = kt * 32 + (lane >> 4) * 8 + i;
    int f = ntile * 16 + (lane & 15);
    int j = k / 320, d = k - j * 320;
    float v = (d < DD) ? W[((size_t)f * kk + j) * DD + d] : 0.f;
    wtp[(size_t)t * 512 + e] = (_Float16)v;
  }
}

// ---------------- Kernel 0b: pack Whh_m / Wih_m into packed-row (unit*4+gate) A-fragments ----
// 28 m-tiles (25 real + 3 zero pad) x 4 ktiles x 64 lanes x f16x8.
// A-frag convention (k_cnn-proven): elem (mt,kt,lane,i) = Apck[mt*16+(lane&15)][kt*32+(lane>>4)*8+i],
// Apck[p][k] = W[(p>>2) + 100*(p&3)][k]  (gate p&3==3 -> 0; k>=100 -> 0).
__global__ __launch_bounds__(256) void k_prep2(const float* __restrict__ Whh,
    const float* __restrict__ Wih, _Float16* __restrict__ wpkW, _Float16* __restrict__ wpkI)
{
  const float* W = (blockIdx.x == 0) ? Whh : Wih;
  _Float16* dst  = (blockIdx.x == 0) ? wpkW : wpkI;
  for (int idx = threadIdx.x; idx < 28 * 4 * 64 * 8; idx += 256){
    int i = idx & 7, lane = (idx >> 3) & 63, kt = (idx >> 9) & 3, mt = idx >> 11;
    int rl = lane & 15, gp = lane >> 4;
    int p = mt * 16 + rl;
    int k = kt * 32 + gp * 8 + i;
    int uu = p >> 2, g = p & 3;
    float v = (mt < 25 && g < 3 && k < 100) ? W[(size_t)(uu + 100 * g) * 100 + k] : 0.f;
    dst[idx] = (_Float16)v;
  }
}

// ---------------- Kernel 1: embedding + TextCNN(3,4,5) via MFMA + max-relu + s_utt ----------------
#define WST 328
__global__ __launch_bounds__(256) void k_cnn(const int* __restrict__ sents,
    const float* __restrict__ emb, const _Float16* __restrict__ wtp,
    const float* __restrict__ bc3, const float* __restrict__ bc4, const float* __restrict__ bc5,
    const float* __restrict__ Wt,  const float* __restrict__ bt,
    float* __restrict__ su)
{
  __shared__ __attribute__((aligned(16))) _Float16 w16[52 * WST];
  __shared__ float feats[192];
  __shared__ int ids[LL];
  const int tid = threadIdx.x;
  const int s = blockIdx.x;

  if (tid < LL) ids[tid] = sents[s * LL + tid];
  for (int e = tid; e < 52 * WST / 2; e += 256) ((u32*)w16)[e] = 0u;
  __syncthreads();
  for (int e = tid; e < LL * 75; e += 256){
    int l = e / 75, d4 = (e - l * 75) * 4;
    float4 v = *(const float4*)&emb[(size_t)ids[l] * DD + d4];
    _Float16* p = &w16[l * WST + d4];
    p[0] = (_Float16)v.x; p[1] = (_Float16)v.y; p[2] = (_Float16)v.z; p[3] = (_Float16)v.w;
  }
  __syncthreads();

  const int lane = tid & 63, wid = tid >> 6;
  const int rl = lane & 15, gp = lane >> 4;
  const int kkstart[3] = {0, 120, 280};
  float fmaxv[3];
  #pragma unroll
  for (int kki = 0; kki < 3; ++kki){
    const int kk = 3 + kki, nkt = kk * 10, Pk = LL - kk + 1;
    f32x4 acc0 = {0.f,0.f,0.f,0.f}, acc1 = acc0, acc2 = acc0;
    const f16x8* bp = (const f16x8*)(wtp + (size_t)(kkstart[kki] + wid * nkt) * 512) + lane;
    int j = 0, d = gp * 8;
    for (int kt = 0; kt < nkt; ++kt){
      f16x8 b  = bp[(size_t)kt * 64];
      f16x8 a0 = *(const f16x8*)&w16[(rl      + j) * WST + d];
      f16x8 a1 = *(const f16x8*)&w16[(16 + rl + j) * WST + d];
      f16x8 a2 = *(const f16x8*)&w16[(32 + rl + j) * WST + d];
      acc0 = __builtin_amdgcn_mfma_f32_16x16x32_f16(a0, b, acc0, 0, 0, 0);
      acc1 = __builtin_amdgcn_mfma_f32_16x16x32_f16(a1, b, acc1, 0, 0, 0);
      acc2 = __builtin_amdgcn_mfma_f32_16x16x32_f16(a2, b, acc2, 0, 0, 0);
      d += 32; if (d >= 320){ d -= 320; ++j; }
    }
    float m = -1e30f;
    #pragma unroll
    for (int r = 0; r < 4; ++r){
      int p0 = gp * 4 + r;
      if (p0 < Pk)      m = fmaxf(m, acc0[r]);
      if (16 + p0 < Pk) m = fmaxf(m, acc1[r]);
      if (32 + p0 < Pk) m = fmaxf(m, acc2[r]);
    }
    m = fmaxf(m, __shfl_xor(m, 16));
    m = fmaxf(m, __shfl_xor(m, 32));
    fmaxv[kki] = m;
  }
  if (lane < 16){
    feats[  0 + wid * 16 + lane] = fmaxv[0];
    feats[ 64 + wid * 16 + lane] = fmaxv[1];
    feats[128 + wid * 16 + lane] = fmaxv[2];
  }
  __syncthreads();
  if (tid < 192){
    float bias = (tid < 64) ? bc3[tid] : ((tid < 128) ? bc4[tid - 64] : bc5[tid - 128]);
    feats[tid] = fmaxf(0.f, feats[tid] + bias);
  }
  __syncthreads();
  if (tid < HH){
    float acc = bt[tid];
    for (int c = 0; c < 192; ++c)
      acc += feats[c] * Wt[c * HH + tid];
    su[(size_t)s * HH + tid] = ftanh(acc);
  }
}

// ---------------- Kernel 2/4: gi = src @ Wih^T + bih   (rows x 300) ----------------
__global__ __launch_bounds__(320) void k_gi(const float* __restrict__ src,
    const float* __restrict__ W, const float* __restrict__ b, float* __restrict__ dst)
{
  __shared__ float x[HH];
  const int t = blockIdx.x, tid = threadIdx.x;
  if (tid < HH) x[tid] = src[(size_t)t * HH + tid];
  __syncthreads();
  if (tid < 300){
    float acc = b[tid];
    const float* wr = W + (size_t)tid * HH;
    #pragma unroll
    for (int i = 0; i < 25; ++i){
      float4 wv = *(const float4*)(wr + 4 * i);
      float4 xv = *(const float4*)&x[4 * i];
      acc += xv.x * wv.x + xv.y * wv.y + xv.z * wv.z + xv.w * wv.w;
    }
    dst[(size_t)t * 300 + tid] = acc;
  }
}

// ---------------- Kernel 3: sequential context-GRU scan (r5 version, best measured) ----------------
#define CH 32
__global__ __launch_bounds__(320, 1) void k_scan(const float* __restrict__ gi,
    const float* __restrict__ Whh, const float* __restrict__ bhh,
    float* __restrict__ hid, int steps)
{
  __shared__ __attribute__((aligned(16))) _Float16 h16[128];
  __shared__ __attribute__((aligned(16))) float gh_l[304];
  __shared__ float gi_buf[CH * 300];
  __shared__ float hid_buf[CH * HH];
  const int tid = threadIdx.x;
  const int lane = tid & 63, wvid = tid >> 6;   // 5 waves
  const int rl = lane & 15, gp = lane >> 4;

  f16x8 afrag[4][4];
  #pragma unroll
  for (int m = 0; m < 4; ++m){
    int mt = wvid + 5 * m;
    int row = mt * 16 + rl;
    #pragma unroll
    for (int kt = 0; kt < 4; ++kt){
      f16x8 f;
      #pragma unroll
      for (int i = 0; i < 8; ++i){
        int k = kt * 32 + gp * 8 + i;
        float v = (row < 300 && k < 100) ? Whh[(size_t)row * 100 + k] : 0.f;
        f[i] = (_Float16)v;
      }
      afrag[m][kt] = f;
    }
  }
  float bhr = 0.f, bhz = 0.f, bhn = 0.f, hreg = 0.f;
  if (tid < HH){ bhr = bhh[tid]; bhz = bhh[tid + 100]; bhn = bhh[tid + 200]; }
  if (tid < 128) h16[tid] = (_Float16)0.f;
  {
    int c0 = (steps < CH ? steps : CH) * 75;
    for (int e = tid; e < c0; e += 320)
      ((float4*)gi_buf)[e] = ((const float4*)gi)[e];
  }
  __syncthreads();

  int t0 = 0;
  while (t0 < steps){
    int cnt = steps - t0; if (cnt > CH) cnt = CH;
    for (int s = 0; s < cnt; ++s){
      {
        const f16x8* hp = (const f16x8*)h16;
        f16x8 bf0 = hp[ 0 + gp], bf1 = hp[ 4 + gp], bf2 = hp[ 8 + gp], bf3 = hp[12 + gp];
        #pragma unroll
        for (int m = 0; m < 4; ++m){
          f32x4 acc = {0.f, 0.f, 0.f, 0.f};
          acc = __builtin_amdgcn_mfma_f32_16x16x32_f16(afrag[m][0], bf0, acc, 0, 0, 0);
          acc = __builtin_amdgcn_mfma_f32_16x16x32_f16(afrag[m][1], bf1, acc, 0, 0, 0);
          acc = __builtin_amdgcn_mfma_f32_16x16x32_f16(afrag[m][2], bf2, acc, 0, 0, 0);
          acc = __builtin_amdgcn_mfma_f32_16x16x32_f16(afrag[m][3], bf3, acc, 0, 0, 0);
          int mt = wvid + 5 * m;
          if (rl == 0 && mt < 19)
            *(float4*)&gh_l[mt * 16 + gp * 4] = *(float4*)&acc;
        }
      }
      __syncthreads();
      if (tid < HH){
        const float* gpp = gi_buf + s * 300;
        float r = sigm(gpp[tid]       + gh_l[tid]       + bhr);
        float z = sigm(gpp[tid + 100] + gh_l[tid + 100] + bhz);
        float n = ftanh(gpp[tid + 200] + r * (gh_l[tid + 200] + bhn));
        float o = (1.f - z) * n + z * hreg;
        hreg = o;
        h16[tid] = (_Float16)o;
        hid_buf[s * HH + tid] = o;
      }
      __syncthreads();
    }
    for (int e = tid; e < cnt * 25; e += 320)
      ((float4*)(hid + (size_t)t0 * HH))[e] = ((const float4*)hid_buf)[e];
    int nt0 = t0 + cnt;
    int ncnt = steps - nt0; if (ncnt > CH) ncnt = CH; if (ncnt < 0) ncnt = 0;
    for (int e = tid; e < ncnt * 75; e += 320)
      ((float4*)gi_buf)[e] = ((const float4*)(gi + (size_t)nt0 * 300))[e];
    __syncthreads();
    t0 = nt0;
  }
}

// ---------------- Kernel 5: BATCHED 3-hop windowed memory attention ----------------
// 8 queries per block, 256 blocks (1 per CU). The mem-GRU matvec is an MFMA GEMM:
// gh(400 packed rows) = WhhPack @ H(100x8 queries) per step — ONE barrier per step
// amortized over 8 queries. D-layout puts r,z,n of unit (mt*4+gp) in one lane's
// acc[0..2] for query j=rl&7; cols 8-15 duplicate 0-7, so lanes rl<8 combine
// tiles 0..3 and rl>=8 combine tiles 4..6 -> all 800 (unit,query) pairs once,
// h carried in registers. gi2: hop0 staged from gm per 8-slot chunk; hop1 =
// MFMA GEMM (WihPack @ MEM-chunk) + bih. Attention phases thread-parallel.
__global__ __launch_bounds__(256, 1) void k_att2(
    const float* __restrict__ su, const float* __restrict__ hid, const float* __restrict__ gm,
    const _Float16* __restrict__ wpkW, const _Float16* __restrict__ wpkI,
    const float* __restrict__ bih, const float* __restrict__ bhh,
    float* __restrict__ scont)
{
  __shared__ __attribute__((aligned(16))) _Float16 MEM[40][8][136];
  __shared__ __attribute__((aligned(16))) _Float16 H16[2][8][136];
  __shared__ __attribute__((aligned(16))) _Float16 GI2[8][8][100][4];
  __shared__ float QL[8][104];
  __shared__ float SC[8][40];

  const int tid = threadIdx.x;
  const int lane = tid & 63, wvid = tid >> 6;   // 4 waves
  const int rl = lane & 15, gp = lane >> 4;
  const int qbase = blockIdx.x * 8;
  const int j = rl & 7;
  const int qi = qbase + j;
  int wminj = 39 - qi; if (wminj < 0) wminj = 0;
  if (qi >= TT - 1) wminj = 40;                 // invalid query -> never valid

  // persistent Whh A-frags: wave owns m-tiles {wvid+4t : t<7} (wpk padded to 28 tiles)
  f16x8 aW[7][4];
  #pragma unroll
  for (int t = 0; t < 7; ++t){
    int mt = wvid + 4 * t;
    #pragma unroll
    for (int kt = 0; kt < 4; ++kt)
      aW[t][kt] = *(const f16x8*)(wpkW + (size_t)((mt * 4 + kt) * 64 + lane) * 8);
  }
  // bih triples for all 7 tiles (GEMM epilogue)
  float bi_[7][3];
  #pragma unroll
  for (int t = 0; t < 7; ++t){
    int mt = wvid + 4 * t;
    bool v = (mt < 25);
    int uu = v ? (mt * 4 + gp) : 0;
    bi_[t][0] = v ? bih[uu]       : 0.f;
    bi_[t][1] = v ? bih[uu + 100] : 0.f;
    bi_[t][2] = v ? bih[uu + 200] : 0.f;
  }
  // combine-role constants: rl<8 -> tiles 0..3, rl>=8 -> tiles 4..6
  const int cbase = (rl < 8) ? 0 : 4;
  float bh_[4][3]; int cu[4]; bool cv[4];
  #pragma unroll
  for (int tt = 0; tt < 4; ++tt){
    int t = cbase + tt;
    int mt = wvid + 4 * t;
    bool v = (t < 7) && (mt < 25);
    cv[tt] = v;
    int uu = v ? (mt * 4 + gp) : 0;
    cu[tt] = uu;
    bh_[tt][0] = v ? bhh[uu]       : 0.f;
    bh_[tt][1] = v ? bhh[uu + 100] : 0.f;
    bh_[tt][2] = v ? bhh[uu + 200] : 0.f;
  }

  // ---- staging: MEM (windowed hiddens, f16, zero-padded), QL, H16 zero ----
  for (int e = tid; e < 40 * 8 * 34; e += 256){
    int i4 = e % 34, wj = e / 34, w = wj >> 3, jj = wj & 7;
    int qq = qbase + jj;
    int row = qq - 39 + w;
    f16x4 v4 = {0, 0, 0, 0};
    if (i4 < 25 && qq < TT - 1 && row >= 0){
      float4 f = *(const float4*)&hid[(size_t)row * HH + i4 * 4];
      v4[0] = (_Float16)f.x; v4[1] = (_Float16)f.y; v4[2] = (_Float16)f.z; v4[3] = (_Float16)f.w;
    }
    *(f16x4*)&MEM[w][jj][i4 * 4] = v4;
  }
  for (int e = tid; e < 8 * 104; e += 256){
    int jj = e / 104, ii = e % 104;
    int qq = qbase + jj;
    QL[jj][ii] = (ii < 100 && qq < TT - 1) ? su[(size_t)(qq + 1) * HH + ii] : 0.f;
  }
  for (int e = tid; e < 2 * 8 * 136; e += 256) ((_Float16*)H16)[e] = (_Float16)0;
  __syncthreads();

  for (int hop = 0; hop < 3; ++hop){
    // --- scores ---
    for (int e = tid; e < 320; e += 256){
      int jj = e / 40, w = e % 40;
      int qq = qbase + jj;
      int wm = 39 - qq; if (wm < 0) wm = 0; if (qq >= TT - 1) wm = 40;
      float acc = 0.f;
      if (w >= wm){
        #pragma unroll
        for (int g = 0; g < 13; ++g){
          f16x8 m8 = *(const f16x8*)&MEM[w][jj][g * 8];
          const float* qp = &QL[jj][g * 8];
          #pragma unroll
          for (int i = 0; i < 8; ++i) acc += (float)m8[i] * qp[i];
        }
        SC[jj][w] = acc;
      } else SC[jj][w] = -1e10f;
    }
    __syncthreads();
    // --- softmax (8 serial threads) ---
    if (tid < 8){
      float m = -3e38f;
      for (int w = 0; w < 40; ++w) m = fmaxf(m, SC[tid][w]);
      float s = 0.f;
      for (int w = 0; w < 40; ++w){ float e = __expf(SC[tid][w] - m); SC[tid][w] = e; s += e; }
      float inv = frcp(s);
      for (int w = 0; w < 40; ++w) SC[tid][w] *= inv;
    }
    __syncthreads();
    // --- context + query update (+ output at hop 2) ---
    for (int e = tid; e < 400; e += 256){
      int jj = e / 50, i2 = e % 50;
      float c0 = 0.f, c1 = 0.f;
      for (int w = 0; w < 40; ++w){
        float a = SC[jj][w];
        f16x2 m2 = *(const f16x2*)&MEM[w][jj][i2 * 2];
        c0 += a * (float)m2.x; c1 += a * (float)m2.y;
      }
      float q0 = ftanh(QL[jj][i2 * 2]     + c0);
      float q1 = ftanh(QL[jj][i2 * 2 + 1] + c1);
      QL[jj][i2 * 2] = q0; QL[jj][i2 * 2 + 1] = q1;
      if (hop == 2){
        int qq = qbase + jj;
        if (qq < TT - 1)
          *(float2*)&scont[(size_t)(qq + 1) * HH + i2 * 2] = make_float2(q0, q1);
      }
    }
    if (hop == 2) break;
    // --- reset scan state ---
    for (int e = tid; e < 800; e += 256) H16[0][e / 100][e % 100] = (_Float16)0;
    float hrg[4] = {0.f, 0.f, 0.f, 0.f};
    __syncthreads();   // also orders context's MEM reads before scan overwrites

    for (int c = 0; c < 5; ++c){
      // ---- stage GI2 chunk (slots 8c..8c+7) ----
      if (hop == 0){
        for (int e = tid; e < 6400; e += 256){
          int s8 = e / 800, jj = (e / 100) & 7, uu = e % 100;
          int qq = qbase + jj;
          int row = qq - 39 + c * 8 + s8;
          f16x4 g4 = {0, 0, 0, 0};
          if (qq < TT - 1 && row >= 0){
            const float* gr = &gm[(size_t)row * 300];
            g4[0] = (_Float16)gr[uu]; g4[1] = (_Float16)gr[uu + 100]; g4[2] = (_Float16)gr[uu + 200];
          }
          *(f16x4*)&GI2[s8][jj][uu][0] = g4;
        }
      } else {
        // GI2 = WihPack @ MEM[8c..8c+7] + bih   (B cols = 8 slots x 8 queries)
        #pragma unroll
        for (int nt = 0; nt < 4; ++nt){
          f16x8 bf[4];
          #pragma unroll
          for (int kt = 0; kt < 4; ++kt)
            bf[kt] = *(const f16x8*)&MEM[c * 8 + nt * 2 + (rl >> 3)][rl & 7][kt * 32 + gp * 8];
          #pragma unroll
          for (int t = 0; t < 7; ++t){
            int mt = wvid + 4 * t;
            if (mt < 25){
              f32x4 ac = {0.f, 0.f, 0.f, 0.f};
              #pragma unroll
              for (int kt = 0; kt < 4; ++kt){
                f16x8 ai = *(const f16x8*)(wpkI + (size_t)((mt * 4 + kt) * 64 + lane) * 8);
                ac = __builtin_amdgcn_mfma_f32_16x16x32_f16(ai, bf[kt], ac, 0, 0, 0);
              }
              int uu = mt * 4 + gp;
              int s8 = nt * 2 + (rl >> 3), jj = rl & 7;
              f16x4 g4;
              g4[0] = (_Float16)(ac[0] + bi_[t][0]);
              g4[1] = (_Float16)(ac[1] + bi_[t][1]);
              g4[2] = (_Float16)(ac[2] + bi_[t][2]);
              g4[3] = (_Float16)0.f;
              *(f16x4*)&GI2[s8][jj][uu][0] = g4;
            }
          }
        }
      }
      __syncthreads();
      // ---- 8 scan steps ----
      for (int s = 0; s < 8; ++s){
        int w = c * 8 + s;
        const _Float16 (*hs)[136] = H16[w & 1];
        _Float16 (*hd)[136] = H16[(w + 1) & 1];
        f16x8 b0 = *(const f16x8*)&hs[j][      gp * 8];
        f16x8 b1 = *(const f16x8*)&hs[j][32  + gp * 8];
        f16x8 b2 = *(const f16x8*)&hs[j][64  + gp * 8];
        f16x8 b3 = *(const f16x8*)&hs[j][96  + gp * 8];
        f32x4 acc[7];
        #pragma unroll
        for (int t = 0; t < 7; ++t){
          int mt = wvid + 4 * t;
          f32x4 a = {0.f, 0.f, 0.f, 0.f};
          if (mt < 25){
            a = __builtin_amdgcn_mfma_f32_16x16x32_f16(aW[t][0], b0, a, 0, 0, 0);
            a = __builtin_amdgcn_mfma_f32_16x16x32_f16(aW[t][1], b1, a, 0, 0, 0);
            a = __builtin_amdgcn_mfma_f32_16x16x32_f16(aW[t][2], b2, a, 0, 0, 0);
            a = __builtin_amdgcn_mfma_f32_16x16x32_f16(aW[t][3], b3, a, 0, 0, 0);
          }
          acc[t] = a;
        }
        const bool vw = (w >= wminj);
        #pragma unroll
        for (int tt = 0; tt < 4; ++tt){
          if (cv[tt]){
            f32x4 ac = (rl < 8) ? acc[tt] : acc[(tt + 4 < 7) ? (tt + 4) : 6];
            f16x4 g4 = *(const f16x4*)&GI2[s][j][cu[tt]][0];
            float r = sigm((float)g4[0] + ac[0] + bh_[tt][0]);
            float z = sigm((float)g4[1] + ac[1] + bh_[tt][1]);
            float n = ftanh((float)g4[2] + r * (ac[2] + bh_[tt][2]));
            float o = vw ? ((1.f - z) * n + z * hrg[tt]) : hrg[tt];
            hrg[tt] = o;
            hd[j][cu[tt]]     = (_Float16)o;
            MEM[w][j][cu[tt]] = (_Float16)o;
          }
        }
        __syncthreads();
      }
    }
  }
}

// ---------------- Kernel 6: classifier + log_softmax ----------------
__global__ __launch_bounds__(256) void k_cls(const float* __restrict__ su, const float* __restrict__ scont,
    const float* __restrict__ Wcls, const float* __restrict__ bcls, float* __restrict__ out)
{
  __shared__ float wl[HH * NCC];
  __shared__ float bl[NCC];
  const int tid = threadIdx.x;
  for (int e = tid; e < HH * NCC; e += 256) wl[e] = Wcls[e];
  if (tid < NCC) bl[tid] = bcls[tid];
  __syncthreads();
  int r = blockIdx.x * 256 + tid;
  if (r < TT){
    const float* v = (r == 0) ? su : (scont + (size_t)r * HH);
    float l[NCC];
    #pragma unroll
    for (int c = 0; c < NCC; ++c) l[c] = bl[c];
    for (int h = 0; h < HH; ++h){
      float x = v[h];
      #pragma unroll
      for (int c = 0; c < NCC; ++c) l[c] += x * wl[h * NCC + c];
    }
    float m = l[0];
    #pragma unroll
    for (int c = 1; c < NCC; ++c) m = fmaxf(m, l[c]);
    float ssum = 0.f;
    #pragma unroll
    for (int c = 0; c < NCC; ++c) ssum += __expf(l[c] - m);
    float lse = m + __logf(ssum);
    #pragma unroll
    for (int c = 0; c < NCC; ++c) out[(size_t)r * NCC + c] = l[c] - lse;
  }
}

extern "C" void kernel_launch(void* const* d_in, const int* in_sizes, int n_in,
                              void* d_out, int out_size, void* d_ws, size_t ws_size,
                              hipStream_t stream)
{
  const int* sents  = (const int*)d_in[0];
  // d_in[1] = lengths (unused by the reference)
  const float* emb    = (const float*)d_in[2];
  const float* Wc3    = (const float*)d_in[3];  const float* bc3 = (const float*)d_in[4];
  const float* Wc4    = (const float*)d_in[5];  const float* bc4 = (const float*)d_in[6];
  const float* Wc5    = (const float*)d_in[7];  const float* bc5 = (const float*)d_in[8];
  const float* Wt     = (const float*)d_in[9];  const float* bt  = (const float*)d_in[10];
  const float* Wih_c  = (const float*)d_in[11]; const float* Whh_c = (const float*)d_in[12];
  const float* bih_c  = (const float*)d_in[13]; const float* bhh_c = (const float*)d_in[14];
  const float* Wih_m  = (const float*)d_in[15]; const float* Whh_m = (const float*)d_in[16];
  const float* bih_m  = (const float*)d_in[17]; const float* bhh_m = (const float*)d_in[18];
  const float* Wcls   = (const float*)d_in[19]; const float* bcls  = (const float*)d_in[20];

  float* ws    = (float*)d_ws;
  float* su    = ws;                  // 2048*100
  float* gic   = su  + 204800;        // 2047*300 (dead after k_scan)
  float* hid   = gic + 614100;        // 2047*100
  float* gm    = gic;                 // aliases gic (gic consumed before gm written)
  float* scont = hid + 204700;        // 2048*100 (row 0 unused)
  _Float16* wtp  = (_Float16*)(scont + 204800);  // 245760 f16 packed conv weights
  _Float16* wpkW = wtp + 245760;                 // 57344 f16 packed Whh_m frags
  _Float16* wpkI = wpkW + 57344;                 // 57344 f16 packed Wih_m frags

  k_prep <<<480,    256, 0, stream>>>(Wc3, Wc4, Wc5, wtp);
  k_prep2<<<2,      256, 0, stream>>>(Whh_m, Wih_m, wpkW, wpkI);
  k_cnn  <<<TT,     256, 0, stream>>>(sents, emb, wtp, bc3, bc4, bc5, Wt, bt, su);
  k_gi   <<<TT - 1, 320, 0, stream>>>(su, Wih_c, bih_c, gic);
  k_scan <<<1,      320, 0, stream>>>(gic, Whh_c, bhh_c, hid, TT - 1);
  k_gi   <<<TT - 1, 320, 0, stream>>>(hid, Wih_m, bih_m, gm);
  k_att2 <<<256,    256, 0, stream>>>(su, hid, gm, wpkW, wpkI, bih_m, bhh_m, scont);
  k_cls  <<<(TT + 255) / 256, 256, 0, stream>>>(su, scont, Wcls, bcls, (float*)d_out);
}

// Round 8
// 1711.901 us; speedup vs baseline: 1.4227x; 1.0190x over previous
//
#include <hip/hip_runtime.h>

#define TT 2048
#define LL 50
#define DD 300
#define HH 100
#define NCC 7

typedef unsigned short u16;
typedef unsigned int u32;
typedef _Float16 f16x2 __attribute__((ext_vector_type(2)));
typedef _Float16 f16x4 __attribute__((ext_vector_type(4)));
typedef _Float16 f16x8 __attribute__((ext_vector_type(8)));
typedef float f32x4 __attribute__((ext_vector_type(4)));

__device__ __forceinline__ float frcp(float x){ return __builtin_amdgcn_rcpf(x); }
__device__ __forceinline__ float sigm(float x){ return frcp(1.f + __expf(-x)); }
__device__ __forceinline__ float ftanh(float x){ return 1.f - 2.f * frcp(1.f + __expf(2.f * x)); }

#if defined(__has_builtin)
#if __has_builtin(__builtin_amdgcn_fdot2)
#define HAS_FDOT2 1
#endif
#endif
__device__ __forceinline__ float fdot2(f16x2 a, f16x2 b, float c){
#ifdef HAS_FDOT2
  return __builtin_amdgcn_fdot2(a, b, c, false);
#else
  return c + (float)a.x * (float)b.x + (float)a.y * (float)b.y;
#endif
}
__device__ __forceinline__ f16x2 pk(float x, float y){ f16x2 r; r.x = (_Float16)x; r.y = (_Float16)y; return r; }

// ---------------- Kernel 0: pack conv weights into MFMA B-fragment order ----------------
__global__ __launch_bounds__(256) void k_prep(const float* __restrict__ Wc3,
    const float* __restrict__ Wc4, const float* __restrict__ Wc5, _Float16* __restrict__ wtp)
{
  const int t = blockIdx.x;
  int kki, ntile, kt;
  if (t < 120){ kki = 0; ntile = t / 30;        kt = t % 30; }
  else if (t < 280){ kki = 1; int r = t - 120; ntile = r / 40; kt = r % 40; }
  else { kki = 2; int r = t - 280;             ntile = r / 50; kt = r % 50; }
  const float* W = (kki == 0) ? Wc3 : ((kki == 1) ? Wc4 : Wc5);
  const int kk = 3 + kki;
  #pragma unroll
  for (int u = 0; u < 2; ++u){
    int e = threadIdx.x * 2 + u;       // 0..511
    int lane = e >> 3, i = e & 7;
    int k = kt * 32 + (lane >> 4) * 8 + i;
    int f = ntile * 16 + (lane & 15);
    int j = k / 320, d = k - j * 320;
    float v = (d < DD) ? W[((size_t)f * kk + j) * DD + d] : 0.f;
    wtp[(size_t)t * 512 + e] = (_Float16)v;
  }
}

// ---------------- Kernel 0b: pack Whh_m / Wih_m into packed-row (unit*4+gate) A-fragments ----
__global__ __launch_bounds__(256) void k_prep2(const float* __restrict__ Whh,
    const float* __restrict__ Wih, _Float16* __restrict__ wpkW, _Float16* __restrict__ wpkI)
{
  const float* W = (blockIdx.x == 0) ? Whh : Wih;
  _Float16* dst  = (blockIdx.x == 0) ? wpkW : wpkI;
  for (int idx = threadIdx.x; idx < 28 * 4 * 64 * 8; idx += 256){
    int i = idx & 7, lane = (idx >> 3) & 63, kt = (idx >> 9) & 3, mt = idx >> 11;
    int rl = lane & 15, gp = lane >> 4;
    int p = mt * 16 + rl;
    int k = kt * 32 + gp * 8 + i;
    int uu = p >> 2, g = p & 3;
    float v = (mt < 25 && g < 3 && k < 100) ? W[(size_t)(uu + 100 * g) * 100 + k] : 0.f;
    dst[idx] = (_Float16)v;
  }
}

// ---------------- Kernel 1: embedding + TextCNN(3,4,5) via MFMA + max-relu + s_utt ----------------
#define WST 328
__global__ __launch_bounds__(256) void k_cnn(const int* __restrict__ sents,
    const float* __restrict__ emb, const _Float16* __restrict__ wtp,
    const float* __restrict__ bc3, const float* __restrict__ bc4, const float* __restrict__ bc5,
    const float* __restrict__ Wt,  const float* __restrict__ bt,
    float* __restrict__ su)
{
  __shared__ __attribute__((aligned(16))) _Float16 w16[52 * WST];
  __shared__ float feats[192];
  __shared__ int ids[LL];
  const int tid = threadIdx.x;
  const int s = blockIdx.x;

  if (tid < LL) ids[tid] = sents[s * LL + tid];
  for (int e = tid; e < 52 * WST / 2; e += 256) ((u32*)w16)[e] = 0u;
  __syncthreads();
  for (int e = tid; e < LL * 75; e += 256){
    int l = e / 75, d4 = (e - l * 75) * 4;
    float4 v = *(const float4*)&emb[(size_t)ids[l] * DD + d4];
    _Float16* p = &w16[l * WST + d4];
    p[0] = (_Float16)v.x; p[1] = (_Float16)v.y; p[2] = (_Float16)v.z; p[3] = (_Float16)v.w;
  }
  __syncthreads();

  const int lane = tid & 63, wid = tid >> 6;
  const int rl = lane & 15, gp = lane >> 4;
  const int kkstart[3] = {0, 120, 280};
  float fmaxv[3];
  #pragma unroll
  for (int kki = 0; kki < 3; ++kki){
    const int kk = 3 + kki, nkt = kk * 10, Pk = LL - kk + 1;
    f32x4 acc0 = {0.f,0.f,0.f,0.f}, acc1 = acc0, acc2 = acc0;
    const f16x8* bp = (const f16x8*)(wtp + (size_t)(kkstart[kki] + wid * nkt) * 512) + lane;
    int j = 0, d = gp * 8;
    for (int kt = 0; kt < nkt; ++kt){
      f16x8 b  = bp[(size_t)kt * 64];
      f16x8 a0 = *(const f16x8*)&w16[(rl      + j) * WST + d];
      f16x8 a1 = *(const f16x8*)&w16[(16 + rl + j) * WST + d];
      f16x8 a2 = *(const f16x8*)&w16[(32 + rl + j) * WST + d];
      acc0 = __builtin_amdgcn_mfma_f32_16x16x32_f16(a0, b, acc0, 0, 0, 0);
      acc1 = __builtin_amdgcn_mfma_f32_16x16x32_f16(a1, b, acc1, 0, 0, 0);
      acc2 = __builtin_amdgcn_mfma_f32_16x16x32_f16(a2, b, acc2, 0, 0, 0);
      d += 32; if (d >= 320){ d -= 320; ++j; }
    }
    float m = -1e30f;
    #pragma unroll
    for (int r = 0; r < 4; ++r){
      int p0 = gp * 4 + r;
      if (p0 < Pk)      m = fmaxf(m, acc0[r]);
      if (16 + p0 < Pk) m = fmaxf(m, acc1[r]);
      if (32 + p0 < Pk) m = fmaxf(m, acc2[r]);
    }
    m = fmaxf(m, __shfl_xor(m, 16));
    m = fmaxf(m, __shfl_xor(m, 32));
    fmaxv[kki] = m;
  }
  if (lane < 16){
    feats[  0 + wid * 16 + lane] = fmaxv[0];
    feats[ 64 + wid * 16 + lane] = fmaxv[1];
    feats[128 + wid * 16 + lane] = fmaxv[2];
  }
  __syncthreads();
  if (tid < 192){
    float bias = (tid < 64) ? bc3[tid] : ((tid < 128) ? bc4[tid - 64] : bc5[tid - 128]);
    feats[tid] = fmaxf(0.f, feats[tid] + bias);
  }
  __syncthreads();
  if (tid < HH){
    float acc = bt[tid];
    for (int c = 0; c < 192; ++c)
      acc += feats[c] * Wt[c * HH + tid];
    su[(size_t)s * HH + tid] = ftanh(acc);
  }
}

// ---------------- Kernel 2/4: gi = src @ W^T + b as an MFMA GEMM ----------------
// src [R][100] f32, W [300][100] f32 (row-major, k contiguous -> B-frags load
// directly, no packing). A-frag: row=lane&15, k=(lane>>4)*8+i (k_cnn-proven).
// D: col=lane&15 (n), row=(lane>>4)*4+reg (m). Grid (32, 2): 64-row m-blocks
// (4 waves x 1 m-tile), n split 10/9 tiles. Bias added in epilogue.
__global__ __launch_bounds__(256) void k_ggi(const float* __restrict__ src, int R,
    const float* __restrict__ W, const float* __restrict__ b, float* __restrict__ dst)
{
  const int tid = threadIdx.x;
  const int lane = tid & 63, wv = tid >> 6;
  const int rl = lane & 15, gp = lane >> 4;
  const int m0 = blockIdx.x * 64 + wv * 16;
  const int nt0 = blockIdx.y * 10;
  const int ntn = (blockIdx.y == 0) ? 10 : 9;

  // A-frags for this wave's 16 rows (f32 -> f16 in-register)
  f16x8 af[4];
  {
    int mrow = m0 + rl; if (mrow >= R) mrow = 0;   // clamp; garbage rows never stored
    const float* sr = src + (size_t)mrow * 100;
    #pragma unroll
    for (int kt = 0; kt < 4; ++kt){
      f16x8 f = {0,0,0,0,0,0,0,0};
      int k0 = kt * 32 + gp * 8;
      if (k0 < 100){
        float4 x = *(const float4*)(sr + k0);
        f[0]=(_Float16)x.x; f[1]=(_Float16)x.y; f[2]=(_Float16)x.z; f[3]=(_Float16)x.w;
        if (k0 + 4 < 100){
          float4 y = *(const float4*)(sr + k0 + 4);
          f[4]=(_Float16)y.x; f[5]=(_Float16)y.y; f[6]=(_Float16)y.z; f[7]=(_Float16)y.w;
        }
      }
      af[kt] = f;
    }
  }

  for (int nt = nt0; nt < nt0 + ntn; ++nt){
    int n = nt * 16 + rl;
    const float* wr = W + (size_t)(n < 300 ? n : 0) * 100;
    f32x4 acc = {0.f,0.f,0.f,0.f};
    #pragma unroll
    for (int kt = 0; kt < 4; ++kt){
      f16x8 bf = {0,0,0,0,0,0,0,0};
      int k0 = kt * 32 + gp * 8;
      if (k0 < 100){
        float4 x = *(const float4*)(wr + k0);
        bf[0]=(_Float16)x.x; bf[1]=(_Float16)x.y; bf[2]=(_Float16)x.z; bf[3]=(_Float16)x.w;
        if (k0 + 4 < 100){
          float4 y = *(const float4*)(wr + k0 + 4);
          bf[4]=(_Float16)y.x; bf[5]=(_Float16)y.y; bf[6]=(_Float16)y.z; bf[7]=(_Float16)y.w;
        }
      }
      acc = __builtin_amdgcn_mfma_f32_16x16x32_f16(af[kt], bf, acc, 0, 0, 0);
    }
    if (n < 300){
      float bias = b[n];
      #pragma unroll
      for (int r = 0; r < 4; ++r){
        int m = m0 + gp * 4 + r;
        if (m < R) dst[(size_t)m * 300 + n] = acc[r] + bias;
      }
    }
  }
}

// ---------------- Kernel 3: sequential context-GRU scan (r5 version, best measured) ----------------
#define CH 32
__global__ __launch_bounds__(320, 1) void k_scan(const float* __restrict__ gi,
    const float* __restrict__ Whh, const float* __restrict__ bhh,
    float* __restrict__ hid, int steps)
{
  __shared__ __attribute__((aligned(16))) _Float16 h16[128];
  __shared__ __attribute__((aligned(16))) float gh_l[304];
  __shared__ float gi_buf[CH * 300];
  __shared__ float hid_buf[CH * HH];
  const int tid = threadIdx.x;
  const int lane = tid & 63, wvid = tid >> 6;   // 5 waves
  const int rl = lane & 15, gp = lane >> 4;

  f16x8 afrag[4][4];
  #pragma unroll
  for (int m = 0; m < 4; ++m){
    int mt = wvid + 5 * m;
    int row = mt * 16 + rl;
    #pragma unroll
    for (int kt = 0; kt < 4; ++kt){
      f16x8 f;
      #pragma unroll
      for (int i = 0; i < 8; ++i){
        int k = kt * 32 + gp * 8 + i;
        float v = (row < 300 && k < 100) ? Whh[(size_t)row * 100 + k] : 0.f;
        f[i] = (_Float16)v;
      }
      afrag[m][kt] = f;
    }
  }
  float bhr = 0.f, bhz = 0.f, bhn = 0.f, hreg = 0.f;
  if (tid < HH){ bhr = bhh[tid]; bhz = bhh[tid + 100]; bhn = bhh[tid + 200]; }
  if (tid < 128) h16[tid] = (_Float16)0.f;
  {
    int c0 = (steps < CH ? steps : CH) * 75;
    for (int e = tid; e < c0; e += 320)
      ((float4*)gi_buf)[e] = ((const float4*)gi)[e];
  }
  __syncthreads();

  int t0 = 0;
  while (t0 < steps){
    int cnt = steps - t0; if (cnt > CH) cnt = CH;
    for (int s = 0; s < cnt; ++s){
      {
        const f16x8* hp = (const f16x8*)h16;
        f16x8 bf0 = hp[ 0 + gp], bf1 = hp[ 4 + gp], bf2 = hp[ 8 + gp], bf3 = hp[12 + gp];
        #pragma unroll
        for (int m = 0; m < 4; ++m){
          f32x4 acc = {0.f, 0.f, 0.f, 0.f};
          acc = __builtin_amdgcn_mfma_f32_16x16x32_f16(afrag[m][0], bf0, acc, 0, 0, 0);
          acc = __builtin_amdgcn_mfma_f32_16x16x32_f16(afrag[m][1], bf1, acc, 0, 0, 0);
          acc = __builtin_amdgcn_mfma_f32_16x16x32_f16(afrag[m][2], bf2, acc, 0, 0, 0);
          acc = __builtin_amdgcn_mfma_f32_16x16x32_f16(afrag[m][3], bf3, acc, 0, 0, 0);
          int mt = wvid + 5 * m;
          if (rl == 0 && mt < 19)
            *(float4*)&gh_l[mt * 16 + gp * 4] = *(float4*)&acc;
        }
      }
      __syncthreads();
      if (tid < HH){
        const float* gpp = gi_buf + s * 300;
        float r = sigm(gpp[tid]       + gh_l[tid]       + bhr);
        float z = sigm(gpp[tid + 100] + gh_l[tid + 100] + bhz);
        float n = ftanh(gpp[tid + 200] + r * (gh_l[tid + 200] + bhn));
        float o = (1.f - z) * n + z * hreg;
        hreg = o;
        h16[tid] = (_Float16)o;
        hid_buf[s * HH + tid] = o;
      }
      __syncthreads();
    }
    for (int e = tid; e < cnt * 25; e += 320)
      ((float4*)(hid + (size_t)t0 * HH))[e] = ((const float4*)hid_buf)[e];
    int nt0 = t0 + cnt;
    int ncnt = steps - nt0; if (ncnt > CH) ncnt = CH; if (ncnt < 0) ncnt = 0;
    for (int e = tid; e < ncnt * 75; e += 320)
      ((float4*)gi_buf)[e] = ((const float4*)(gi + (size_t)nt0 * 300))[e];
    __syncthreads();
    t0 = nt0;
  }
}

// ---------------- Kernel 5: BATCHED 3-hop windowed memory attention ----------------
__global__ __launch_bounds__(256, 1) void k_att2(
    const float* __restrict__ su, const float* __restrict__ hid, const float* __restrict__ gm,
    const _Float16* __restrict__ wpkW, const _Float16* __restrict__ wpkI,
    const float* __restrict__ bih, const float* __restrict__ bhh,
    float* __restrict__ scont)
{
  __shared__ __attribute__((aligned(16))) _Float16 MEM[40][8][136];
  __shared__ __attribute__((aligned(16))) _Float16 H16[2][8][136];
  __shared__ __attribute__((aligned(16))) _Float16 GI2[8][8][100][4];
  __shared__ float QL[8][104];
  __shared__ float SC[8][40];

  const int tid = threadIdx.x;
  const int lane = tid & 63, wvid = tid >> 6;   // 4 waves
  const int rl = lane & 15, gp = lane >> 4;
  const int qbase = blockIdx.x * 8;
  const int j = rl & 7;
  const int qi = qbase + j;
  int wminj = 39 - qi; if (wminj < 0) wminj = 0;
  if (qi >= TT - 1) wminj = 40;                 // invalid query -> never valid

  f16x8 aW[7][4];
  #pragma unroll
  for (int t = 0; t < 7; ++t){
    int mt = wvid + 4 * t;
    #pragma unroll
    for (int kt = 0; kt < 4; ++kt)
      aW[t][kt] = *(const f16x8*)(wpkW + (size_t)((mt * 4 + kt) * 64 + lane) * 8);
  }
  float bi_[7][3];
  #pragma unroll
  for (int t = 0; t < 7; ++t){
    int mt = wvid + 4 * t;
    bool v = (mt < 25);
    int uu = v ? (mt * 4 + gp) : 0;
    bi_[t][0] = v ? bih[uu]       : 0.f;
    bi_[t][1] = v ? bih[uu + 100] : 0.f;
    bi_[t][2] = v ? bih[uu + 200] : 0.f;
  }
  const int cbase = (rl < 8) ? 0 : 4;
  float bh_[4][3]; int cu[4]; bool cv[4];
  #pragma unroll
  for (int tt = 0; tt < 4; ++tt){
    int t = cbase + tt;
    int mt = wvid + 4 * t;
    bool v = (t < 7) && (mt < 25);
    cv[tt] = v;
    int uu = v ? (mt * 4 + gp) : 0;
    cu[tt] = uu;
    bh_[tt][0] = v ? bhh[uu]       : 0.f;
    bh_[tt][1] = v ? bhh[uu + 100] : 0.f;
    bh_[tt][2] = v ? bhh[uu + 200] : 0.f;
  }

  for (int e = tid; e < 40 * 8 * 34; e += 256){
    int i4 = e % 34, wj = e / 34, w = wj >> 3, jj = wj & 7;
    int qq = qbase + jj;
    int row = qq - 39 + w;
    f16x4 v4 = {0, 0, 0, 0};
    if (i4 < 25 && qq < TT - 1 && row >= 0){
      float4 f = *(const float4*)&hid[(size_t)row * HH + i4 * 4];
      v4[0] = (_Float16)f.x; v4[1] = (_Float16)f.y; v4[2] = (_Float16)f.z; v4[3] = (_Float16)f.w;
    }
    *(f16x4*)&MEM[w][jj][i4 * 4] = v4;
  }
  for (int e = tid; e < 8 * 104; e += 256){
    int jj = e / 104, ii = e % 104;
    int qq = qbase + jj;
    QL[jj][ii] = (ii < 100 && qq < TT - 1) ? su[(size_t)(qq + 1) * HH + ii] : 0.f;
  }
  for (int e = tid; e < 2 * 8 * 136; e += 256) ((_Float16*)H16)[e] = (_Float16)0;
  __syncthreads();

  for (int hop = 0; hop < 3; ++hop){
    for (int e = tid; e < 320; e += 256){
      int jj = e / 40, w = e % 40;
      int qq = qbase + jj;
      int wm = 39 - qq; if (wm < 0) wm = 0; if (qq >= TT - 1) wm = 40;
      float acc = 0.f;
      if (w >= wm){
        #pragma unroll
        for (int g = 0; g < 13; ++g){
          f16x8 m8 = *(const f16x8*)&MEM[w][jj][g * 8];
          const float* qp = &QL[jj][g * 8];
          #pragma unroll
          for (int i = 0; i < 8; ++i) acc += (float)m8[i] * qp[i];
        }
        SC[jj][w] = acc;
      } else SC[jj][w] = -1e10f;
    }
    __syncthreads();
    if (tid < 8){
      float m = -3e38f;
      for (int w = 0; w < 40; ++w) m = fmaxf(m, SC[tid][w]);
      float s = 0.f;
      for (int w = 0; w < 40; ++w){ float e = __expf(SC[tid][w] - m); SC[tid][w] = e; s += e; }
      float inv = frcp(s);
      for (int w = 0; w < 40; ++w) SC[tid][w] *= inv;
    }
    __syncthreads();
    for (int e = tid; e < 400; e += 256){
      int jj = e / 50, i2 = e % 50;
      float c0 = 0.f, c1 = 0.f;
      for (int w = 0; w < 40; ++w){
        float a = SC[jj][w];
        f16x2 m2 = *(const f16x2*)&MEM[w][jj][i2 * 2];
        c0 += a * (float)m2.x; c1 += a * (float)m2.y;
      }
      float q0 = ftanh(QL[jj][i2 * 2]     + c0);
      float q1 = ftanh(QL[jj][i2 * 2 + 1] + c1);
      QL[jj][i2 * 2] = q0; QL[jj][i2 * 2 + 1] = q1;
      if (hop == 2){
        int qq = qbase + jj;
        if (qq < TT - 1)
          *(float2*)&scont[(size_t)(qq + 1) * HH + i2 * 2] = make_float2(q0, q1);
      }
    }
    if (hop == 2) break;
    for (int e = tid; e < 800; e += 256) H16[0][e / 100][e % 100] = (_Float16)0;
    float hrg[4] = {0.f, 0.f, 0.f, 0.f};
    __syncthreads();

    for (int c = 0; c < 5; ++c){
      if (hop == 0){
        for (int e = tid; e < 6400; e += 256){
          int s8 = e / 800, jj = (e / 100) & 7, uu = e % 100;
          int qq = qbase + jj;
          int row = qq - 39 + c * 8 + s8;
          f16x4 g4 = {0, 0, 0, 0};
          if (qq < TT - 1 && row >= 0){
            const float* gr = &gm[(size_t)row * 300];
            g4[0] = (_Float16)gr[uu]; g4[1] = (_Float16)gr[uu + 100]; g4[2] = (_Float16)gr[uu + 200];
          }
          *(f16x4*)&GI2[s8][jj][uu][0] = g4;
        }
      } else {
        #pragma unroll
        for (int nt = 0; nt < 4; ++nt){
          f16x8 bf[4];
          #pragma unroll
          for (int kt = 0; kt < 4; ++kt)
            bf[kt] = *(const f16x8*)&MEM[c * 8 + nt * 2 + (rl >> 3)][rl & 7][kt * 32 + gp * 8];
          #pragma unroll
          for (int t = 0; t < 7; ++t){
            int mt = wvid + 4 * t;
            if (mt < 25){
              f32x4 ac = {0.f, 0.f, 0.f, 0.f};
              #pragma unroll
              for (int kt = 0; kt < 4; ++kt){
                f16x8 ai = *(const f16x8*)(wpkI + (size_t)((mt * 4 + kt) * 64 + lane) * 8);
                ac = __builtin_amdgcn_mfma_f32_16x16x32_f16(ai, bf[kt], ac, 0, 0, 0);
              }
              int uu = mt * 4 + gp;
              int s8 = nt * 2 + (rl >> 3), jj = rl & 7;
              f16x4 g4;
              g4[0] = (_Float16)(ac[0] + bi_[t][0]);
              g4[1] = (_Float16)(ac[1] + bi_[t][1]);
              g4[2] = (_Float16)(ac[2] + bi_[t][2]);
              g4[3] = (_Float16)0.f;
              *(f16x4*)&GI2[s8][jj][uu][0] = g4;
            }
          }
        }
      }
      __syncthreads();
      for (int s = 0; s < 8; ++s){
        int w = c * 8 + s;
        const _Float16 (*hs)[136] = H16[w & 1];
        _Float16 (*hd)[136] = H16[(w + 1) & 1];
        f16x8 b0 = *(const f16x8*)&hs[j][      gp * 8];
        f16x8 b1 = *(const f16x8*)&hs[j][32  + gp * 8];
        f16x8 b2 = *(const f16x8*)&hs[j][64  + gp * 8];
        f16x8 b3 = *(const f16x8*)&hs[j][96  + gp * 8];
        f32x4 acc[7];
        #pragma unroll
        for (int t = 0; t < 7; ++t){
          int mt = wvid + 4 * t;
          f32x4 a = {0.f, 0.f, 0.f, 0.f};
          if (mt < 25){
            a = __builtin_amdgcn_mfma_f32_16x16x32_f16(aW[t][0], b0, a, 0, 0, 0);
            a = __builtin_amdgcn_mfma_f32_16x16x32_f16(aW[t][1], b1, a, 0, 0, 0);
            a = __builtin_amdgcn_mfma_f32_16x16x32_f16(aW[t][2], b2, a, 0, 0, 0);
            a = __builtin_amdgcn_mfma_f32_16x16x32_f16(aW[t][3], b3, a, 0, 0, 0);
          }
          acc[t] = a;
        }
        const bool vw = (w >= wminj);
        #pragma unroll
        for (int tt = 0; tt < 4; ++tt){
          if (cv[tt]){
            f32x4 ac = (rl < 8) ? acc[tt] : acc[(tt + 4 < 7) ? (tt + 4) : 6];
            f16x4 g4 = *(const f16x4*)&GI2[s][j][cu[tt]][0];
            float r = sigm((float)g4[0] + ac[0] + bh_[tt][0]);
            float z = sigm((float)g4[1] + ac[1] + bh_[tt][1]);
            float n = ftanh((float)g4[2] + r * (ac[2] + bh_[tt][2]));
            float o = vw ? ((1.f - z) * n + z * hrg[tt]) : hrg[tt];
            hrg[tt] = o;
            hd[j][cu[tt]]     = (_Float16)o;
            MEM[w][j][cu[tt]] = (_Float16)o;
          }
        }
        __syncthreads();
      }
    }
  }
}

// ---------------- Kernel 6: classifier + log_softmax ----------------
__global__ __launch_bounds__(256) void k_cls(const float* __restrict__ su, const float* __restrict__ scont,
    const float* __restrict__ Wcls, const float* __restrict__ bcls, float* __restrict__ out)
{
  __shared__ float wl[HH * NCC];
  __shared__ float bl[NCC];
  const int tid = threadIdx.x;
  for (int e = tid; e < HH * NCC; e += 256) wl[e] = Wcls[e];
  if (tid < NCC) bl[tid] = bcls[tid];
  __syncthreads();
  int r = blockIdx.x * 256 + tid;
  if (r < TT){
    const float* v = (r == 0) ? su : (scont + (size_t)r * HH);
    float l[NCC];
    #pragma unroll
    for (int c = 0; c < NCC; ++c) l[c] = bl[c];
    for (int h = 0; h < HH; ++h){
      float x = v[h];
      #pragma unroll
      for (int c = 0; c < NCC; ++c) l[c] += x * wl[h * NCC + c];
    }
    float m = l[0];
    #pragma unroll
    for (int c = 1; c < NCC; ++c) m = fmaxf(m, l[c]);
    float ssum = 0.f;
    #pragma unroll
    for (int c = 0; c < NCC; ++c) ssum += __expf(l[c] - m);
    float lse = m + __logf(ssum);
    #pragma unroll
    for (int c = 0; c < NCC; ++c) out[(size_t)r * NCC + c] = l[c] - lse;
  }
}

extern "C" void kernel_launch(void* const* d_in, const int* in_sizes, int n_in,
                              void* d_out, int out_size, void* d_ws, size_t ws_size,
                              hipStream_t stream)
{
  const int* sents  = (const int*)d_in[0];
  // d_in[1] = lengths (unused by the reference)
  const float* emb    = (const float*)d_in[2];
  const float* Wc3    = (const float*)d_in[3];  const float* bc3 = (const float*)d_in[4];
  const float* Wc4    = (const float*)d_in[5];  const float* bc4 = (const float*)d_in[6];
  const float* Wc5    = (const float*)d_in[7];  const float* bc5 = (const float*)d_in[8];
  const float* Wt     = (const float*)d_in[9];  const float* bt  = (const float*)d_in[10];
  const float* Wih_c  = (const float*)d_in[11]; const float* Whh_c = (const float*)d_in[12];
  const float* bih_c  = (const float*)d_in[13]; const float* bhh_c = (const float*)d_in[14];
  const float* Wih_m  = (const float*)d_in[15]; const float* Whh_m = (const float*)d_in[16];
  const float* bih_m  = (const float*)d_in[17]; const float* bhh_m = (const float*)d_in[18];
  const float* Wcls   = (const float*)d_in[19]; const float* bcls  = (const float*)d_in[20];

  float* ws    = (float*)d_ws;
  float* su    = ws;                  // 2048*100
  float* gic   = su  + 204800;        // 2047*300 (dead after k_scan)
  float* hid   = gic + 614100;        // 2047*100
  float* gm    = gic;                 // aliases gic (gic consumed before gm written)
  float* scont = hid + 204700;        // 2048*100 (row 0 unused)
  _Float16* wtp  = (_Float16*)(scont + 204800);  // 245760 f16 packed conv weights
  _Float16* wpkW = wtp + 245760;                 // 57344 f16 packed Whh_m frags
  _Float16* wpkI = wpkW + 57344;                 // 57344 f16 packed Wih_m frags

  k_prep <<<480,    256, 0, stream>>>(Wc3, Wc4, Wc5, wtp);
  k_prep2<<<2,      256, 0, stream>>>(Whh_m, Wih_m, wpkW, wpkI);
  k_cnn  <<<TT,     256, 0, stream>>>(sents, emb, wtp, bc3, bc4, bc5, Wt, bt, su);
  k_ggi  <<<dim3(32, 2), 256, 0, stream>>>(su, TT - 1, Wih_c, bih_c, gic);
  k_scan <<<1,      320, 0, stream>>>(gic, Whh_c, bhh_c, hid, TT - 1);
  k_ggi  <<<dim3(32, 2), 256, 0, stream>>>(hid, TT - 1, Wih_m, bih_m, gm);
  k_att2 <<<256,    256, 0, stream>>>(su, hid, gm, wpkW, wpkI, bih_m, bhh_m, scont);
  k_cls  <<<(TT + 255) / 256, 256, 0, stream>>>(su, scont, Wcls, bcls, (float*)d_out);
}